// Round 24
// baseline (220.474 us; speedup 1.0000x reference)
//
#include <hip/hip_runtime.h>
#include <hip/hip_bf16.h>

// ---------------------------------------------------------------------------
// ResidualBlock: GMMConv(x)->BN->ELU->GMMConv->BN  +  GMMConv_sc(x)->BN ; ELU
// N=50000, E=800000, C=64, K_main=5, K_sc=1.
// Round 24: fix round-23 compile error - __builtin_nontemporal_store needs an
// ext_vector type, not HIP's uint4 struct. Store via u32x4 alias. Otherwise
// identical to round 23 (= round-21 best + nontemporal scatter stores).
// ---------------------------------------------------------------------------

#define EPS_SIGMA 1e-15f
#define BN_EPS    1e-5f
#define PAD       48

typedef unsigned short ushortT;
typedef unsigned int uintT;
typedef __attribute__((ext_vector_type(8))) short bf16x8;
typedef __attribute__((ext_vector_type(4))) float f32x4;
typedef __attribute__((ext_vector_type(2))) float f32x2;
typedef __attribute__((ext_vector_type(4))) uintT u32x4;

__device__ __forceinline__ ushortT f2bf(float f) {
  uintT b = __float_as_uint(f);
  b += 0x7FFFu + ((b >> 16) & 1u);   // round-to-nearest-even
  return (ushortT)(b >> 16);
}
__device__ __forceinline__ float bf2f(ushortT u) {
  return __uint_as_float(((uintT)u) << 16);
}
__device__ __forceinline__ uintT pk2(float a, float b) {
  return (uintT)f2bf(a) | ((uintT)f2bf(b) << 16);
}

// --- B prep helper: pack [G;root] into MFMA B-fragment layout (bf16) --------
__device__ __forceinline__ void prep_one(const float* __restrict__ g,
                                         const float* __restrict__ root,
                                         ushortT* __restrict__ Bm, int K, int t) {
  int ks = t >> 8, rem = t & 255;
  int nt = rem >> 6, lane = rem & 63;
  int kbase = ks * 32 + (lane >> 4) * 8;
  int col = nt * 16 + (lane & 15);
  ushortT o[8];
#pragma unroll
  for (int j = 0; j < 8; ++j) {
    int r = kbase + j;
    float v;
    if (r < K * 64) {
      int k = r >> 6, i = r & 63;
      v = g[(size_t)i * (K * 64) + k * 64 + col];
    } else {
      v = root[(size_t)(r - K * 64) * 64 + col];
    }
    o[j] = f2bf(v);
  }
  *(uint4*)&Bm[(size_t)t * 8] = *(const uint4*)o;
}

// --- prologue: x->bf16, zero cnt/stats, detect dtype, prep B matrices -------
__global__ void prologue(const float* __restrict__ x, ushortT* __restrict__ x_bf,
                         int total, int* __restrict__ cnt, float* __restrict__ stats,
                         int n, const void* ei, int* flag,
                         const float* g1, const float* root1, ushortT* Bm1,
                         const float* g2, const float* root2, ushortT* Bm2,
                         const float* gs, const float* roots, ushortT* Bmsc) {
  int t = blockIdx.x * 256 + threadIdx.x;
  int idx = t * 4;
  if (idx + 3 < total) {
    float4 v = *(const float4*)&x[idx];
    ushortT o[4] = {f2bf(v.x), f2bf(v.y), f2bf(v.z), f2bf(v.w)};
    *(uint2*)&x_bf[idx] = *(const uint2*)o;
  }
  if (t < n) cnt[t] = 0;
  if (t < 12 * 64) stats[t] = 0.f;
  if (blockIdx.x < 12) prep_one(g1, root1, Bm1, 5, t);
  else if (blockIdx.x < 24) prep_one(g2, root2, Bm2, 5, t - 12 * 256);
  else if (blockIdx.x < 28) prep_one(gs, roots, Bmsc, 1, t - 24 * 256);
  else if (blockIdx.x == 28) {
    const int* p = (const int*)ei;
    __shared__ int bad;
    if (threadIdx.x == 0) bad = 0;
    __syncthreads();
    if (p[threadIdx.x * 2 + 1] != 0) atomicAdd(&bad, 1);
    __syncthreads();
    if (threadIdx.x == 0) *flag = (bad == 0);  // 1 => int64 layout
  }
}

__device__ __forceinline__ int load_idx(const void* ei, size_t pos, int is64) {
  if (is64) return (int)((const long long*)ei)[pos];
  return ((const int*)ei)[pos];
}

// --- scatter + gaussian weights: 32B combined slot, nontemporal stores ------
__global__ __launch_bounds__(256) void scatter_wgt(
    const void* ei, const float* __restrict__ ea, int E, const int* flag,
    int* __restrict__ cnt,
    const float* __restrict__ mu1, const float* __restrict__ sig1,
    const float* __restrict__ mus, const float* __restrict__ sigs,
    const float* __restrict__ mu2, const float* __restrict__ sig2,
    uint4* __restrict__ wbufC) {
  int e = blockIdx.x * 256 + threadIdx.x;
  if (e >= E) return;
  int is64 = *flag;
  int s = load_idx(ei, (size_t)e, is64);
  int d = load_idx(ei, (size_t)E + e, is64);
  float p = ea[e];
  // atomic first: round-trip overlaps the 11 independent exps below
  int pos = atomicAdd(&cnt[d], 1);
  float w1[6], w2[5];
#pragma unroll
  for (int k = 0; k < 5; ++k) {
    float sg = sig1[k], df = p - mu1[k];
    w1[k] = __expf(-0.5f / (EPS_SIGMA + sg * sg) * df * df);
  }
  {
    float sg = sigs[0], df = p - mus[0];
    w1[5] = __expf(-0.5f / (EPS_SIGMA + sg * sg) * df * df);
  }
#pragma unroll
  for (int k = 0; k < 5; ++k) {
    float sg = sig2[k], df = p - mu2[k];
    w2[k] = __expf(-0.5f / (EPS_SIGMA + sg * sg) * df * df);
  }
  if (pos < PAD) {
    size_t slot = (size_t)d * PAD + pos;
    u32x4 r0 = (u32x4){pk2(w1[0], w1[1]), pk2(w1[2], w1[3]),
                       pk2(w1[4], w1[5]), (uintT)s};
    u32x4 r1 = (u32x4){pk2(w2[0], w2[1]), pk2(w2[2], w2[3]),
                       pk2(w2[4], 0.f), (uintT)s};
    u32x4* base = (u32x4*)wbufC;
    __builtin_nontemporal_store(r0, &base[slot * 2 + 0]);
    __builtin_nontemporal_store(r1, &base[slot * 2 + 1]);
  }
}

// --- aggregation: QUARTER-wave per node; lane = 4 channels; no cross-lane ---
template <int KT>
__device__ __forceinline__ void q_fma(f32x2* acc, uint4 r, uint2 xv) {
  f32x2 xlo, xhi;
  xlo.x = bf2f((ushortT)(xv.x & 0xffffu));
  xlo.y = bf2f((ushortT)(xv.x >> 16));
  xhi.x = bf2f((ushortT)(xv.y & 0xffffu));
  xhi.y = bf2f((ushortT)(xv.y >> 16));
  float w;
  f32x2 wv;
  w = bf2f((ushortT)(r.x & 0xffffu));
  wv.x = w; wv.y = w;
  acc[0] = __builtin_elementwise_fma(wv, xlo, acc[0]);
  acc[1] = __builtin_elementwise_fma(wv, xhi, acc[1]);
  if (KT > 1) {
    w = bf2f((ushortT)(r.x >> 16));
    wv.x = w; wv.y = w;
    acc[2] = __builtin_elementwise_fma(wv, xlo, acc[2]);
    acc[3] = __builtin_elementwise_fma(wv, xhi, acc[3]);
  }
  if (KT > 2) {
    w = bf2f((ushortT)(r.y & 0xffffu));
    wv.x = w; wv.y = w;
    acc[4] = __builtin_elementwise_fma(wv, xlo, acc[4]);
    acc[5] = __builtin_elementwise_fma(wv, xhi, acc[5]);
  }
  if (KT > 3) {
    w = bf2f((ushortT)(r.y >> 16));
    wv.x = w; wv.y = w;
    acc[6] = __builtin_elementwise_fma(wv, xlo, acc[6]);
    acc[7] = __builtin_elementwise_fma(wv, xhi, acc[7]);
  }
  if (KT > 4) {
    w = bf2f((ushortT)(r.z & 0xffffu));
    wv.x = w; wv.y = w;
    acc[8] = __builtin_elementwise_fma(wv, xlo, acc[8]);
    acc[9] = __builtin_elementwise_fma(wv, xhi, acc[9]);
  }
  if (KT > 5) {
    w = bf2f((ushortT)(r.z >> 16));
    wv.x = w; wv.y = w;
    acc[10] = __builtin_elementwise_fma(wv, xlo, acc[10]);
    acc[11] = __builtin_elementwise_fma(wv, xhi, acc[11]);
  }
}

// off = 0 (layer1+sc record) or 1 (layer2 record) within each 32B slot
template <int KT>
__global__ __launch_bounds__(256) void agg_pre(const ushortT* __restrict__ feat,
                                               const int* __restrict__ cnt,
                                               const uint4* __restrict__ wbufC, int off,
                                               ushortT* __restrict__ out, int n, int ldo) {
  int lane = threadIdx.x & 63;
  int q = lane >> 4;     // quarter index: which node of this wave's 4
  int c4 = lane & 15;    // channel group: channels 4*c4 .. 4*c4+3
  int node = (blockIdx.x * 4 + (threadIdx.x >> 6)) * 4 + q;  // 16 nodes/block
  bool act = node < n;
  int deg = act ? cnt[node] : 0;
  int cap = deg < PAD ? deg : PAD;
  int beg = node * PAD;
  int end = beg + cap;
  f32x2 acc[2 * KT];
#pragma unroll
  for (int k = 0; k < 2 * KT; ++k) acc[k] = (f32x2){0.f, 0.f};
  int i = beg;
  // unroll 4: per quarter 4 records + 4 gathers in flight (16 loads/wave)
  for (; i + 4 <= end; i += 4) {
    uint4 r0 = wbufC[(size_t)(i + 0) * 2 + off];
    uint4 r1 = wbufC[(size_t)(i + 1) * 2 + off];
    uint4 r2 = wbufC[(size_t)(i + 2) * 2 + off];
    uint4 r3 = wbufC[(size_t)(i + 3) * 2 + off];
    uint2 x0 = *(const uint2*)&feat[((size_t)r0.w << 6) + c4 * 4];
    uint2 x1 = *(const uint2*)&feat[((size_t)r1.w << 6) + c4 * 4];
    uint2 x2 = *(const uint2*)&feat[((size_t)r2.w << 6) + c4 * 4];
    uint2 x3 = *(const uint2*)&feat[((size_t)r3.w << 6) + c4 * 4];
    q_fma<KT>(acc, r0, x0);
    q_fma<KT>(acc, r1, x1);
    q_fma<KT>(acc, r2, x2);
    q_fma<KT>(acc, r3, x3);
  }
  for (; i < end; ++i) {
    uint4 r = wbufC[(size_t)i * 2 + off];
    uint2 xv = *(const uint2*)&feat[((size_t)r.w << 6) + c4 * 4];
    q_fma<KT>(acc, r, xv);
  }
  if (act) {
    float invdeg = 1.0f / (float)(deg > 1 ? deg : 1);
    uintT* outu = (uintT*)out;
    size_t obase = ((size_t)node * ldo) >> 1;
#pragma unroll
    for (int k = 0; k < KT; ++k) {
      uint2 ov = make_uint2(pk2(acc[2 * k].x * invdeg, acc[2 * k].y * invdeg),
                            pk2(acc[2 * k + 1].x * invdeg, acc[2 * k + 1].y * invdeg));
      *(uint2*)&outu[obase + k * 32 + c4 * 2] = ov;
    }
  }
}

// --- BN-stats epilogue helper (device, per-block) ---------------------------
__device__ __forceinline__ void bn_epilogue(float cs[4], float cq[4], int wid, int lane,
                                            int tid, float red_s[4][64], float red_q[4][64],
                                            float* sums, float* sumsq) {
#pragma unroll
  for (int nt = 0; nt < 4; ++nt) {
    cs[nt] += __shfl_xor(cs[nt], 16);
    cs[nt] += __shfl_xor(cs[nt], 32);
    cq[nt] += __shfl_xor(cq[nt], 16);
    cq[nt] += __shfl_xor(cq[nt], 32);
  }
  if (lane < 16) {
#pragma unroll
    for (int nt = 0; nt < 4; ++nt) {
      red_s[wid][nt * 16 + lane] = cs[nt];
      red_q[wid][nt * 16 + lane] = cq[nt];
    }
  }
  __syncthreads();
  if (tid < 64) {
    float ts = red_s[0][tid] + red_s[1][tid] + red_s[2][tid] + red_s[3][tid];
    float tq = red_q[0][tid] + red_q[1][tid] + red_q[2][tid] + red_q[3][tid];
    atomicAdd(&sums[tid], ts);
    atomicAdd(&sumsq[tid], tq);
  }
  __syncthreads();
}

// --- MFMA GEMM (single): Cbf[M,64] = [A1(K1)|A2(64)]@B + bias ; BN stats ----
__global__ __launch_bounds__(256) void gemm_mfma(const ushortT* __restrict__ A1, int lda1,
                                                 int K1, const ushortT* __restrict__ A2,
                                                 const ushortT* __restrict__ Bm,
                                                 const float* __restrict__ bias,
                                                 ushortT* __restrict__ C, int M,
                                                 float* sums, float* sumsq) {
  __shared__ float red_s[4][64];
  __shared__ float red_q[4][64];
  int tid = threadIdx.x;
  int wid = tid >> 6, lane = tid & 63;
  int row16 = lane & 15, kg = lane >> 4;
  int rowbase = blockIdx.x * 64 + wid * 16;
  int arow = rowbase + row16;
  if (arow >= M) arow = M - 1;
  const ushortT* a1p = A1 + (size_t)arow * lda1 + kg * 8;
  const ushortT* a2p = A2 + (size_t)arow * 64 + kg * 8;
  int nks1 = K1 >> 5;
  int nks = (K1 + 64) >> 5;
  f32x4 acc[4];
#pragma unroll
  for (int nt = 0; nt < 4; ++nt) acc[nt] = (f32x4){0.f, 0.f, 0.f, 0.f};
  for (int ks = 0; ks < nks; ++ks) {
    const ushortT* ap = (ks < nks1) ? (a1p + ks * 32) : (a2p + (ks - nks1) * 32);
    bf16x8 af = *(const bf16x8*)ap;
#pragma unroll
    for (int nt = 0; nt < 4; ++nt) {
      bf16x8 bfr = *(const bf16x8*)(Bm + (size_t)ks * 2048 + nt * 512 + lane * 8);
      acc[nt] = __builtin_amdgcn_mfma_f32_16x16x32_bf16(af, bfr, acc[nt], 0, 0, 0);
    }
  }
  float bv[4];
#pragma unroll
  for (int nt = 0; nt < 4; ++nt) bv[nt] = bias[nt * 16 + row16];
  float cs[4] = {}, cq[4] = {};
#pragma unroll
  for (int r = 0; r < 4; ++r) {
    int orow = rowbase + kg * 4 + r;
    if (orow < M) {
#pragma unroll
      for (int nt = 0; nt < 4; ++nt) {
        float v = acc[nt][r] + bv[nt];
        C[(size_t)orow * 64 + nt * 16 + row16] = f2bf(v);
        cs[nt] += v;
        cq[nt] = fmaf(v, v, cq[nt]);
      }
    }
  }
  bn_epilogue(cs, cq, wid, lane, tid, red_s, red_q, sums, sumsq);
}

// --- MFMA GEMM (dual): Hbf = [Abuf|x]@Bm1+b1 ; Sbf = [Abuf_sc|x]@Bmsc+bs ----
__global__ __launch_bounds__(256) void gemm_mfma_dual(
    const ushortT* __restrict__ Abuf, const ushortT* __restrict__ X,
    const ushortT* __restrict__ Bm1, const ushortT* __restrict__ Bmsc,
    const float* __restrict__ b1, const float* __restrict__ bs,
    ushortT* __restrict__ H, ushortT* __restrict__ S, int M,
    float* sumH, float* sqH, float* sumS, float* sqS) {
  __shared__ float red_s[4][64];
  __shared__ float red_q[4][64];
  int tid = threadIdx.x;
  int wid = tid >> 6, lane = tid & 63;
  int row16 = lane & 15, kg = lane >> 4;
  int rowbase = blockIdx.x * 64 + wid * 16;
  int arow = rowbase + row16;
  if (arow >= M) arow = M - 1;
  const ushortT* ab = Abuf + (size_t)arow * 384 + kg * 8;
  const ushortT* xb = X + (size_t)arow * 64 + kg * 8;
  f32x4 accH[4], accS[4];
#pragma unroll
  for (int nt = 0; nt < 4; ++nt) {
    accH[nt] = (f32x4){0.f, 0.f, 0.f, 0.f};
    accS[nt] = (f32x4){0.f, 0.f, 0.f, 0.f};
  }
  for (int ks = 0; ks < 10; ++ks) {
    bf16x8 af = *(const bf16x8*)(ab + ks * 32);
#pragma unroll
    for (int nt = 0; nt < 4; ++nt) {
      bf16x8 bfr = *(const bf16x8*)(Bm1 + (size_t)ks * 2048 + nt * 512 + lane * 8);
      accH[nt] = __builtin_amdgcn_mfma_f32_16x16x32_bf16(af, bfr, accH[nt], 0, 0, 0);
    }
  }
#pragma unroll
  for (int ks = 0; ks < 2; ++ks) {
    bf16x8 af = *(const bf16x8*)(ab + 320 + ks * 32);
#pragma unroll
    for (int nt = 0; nt < 4; ++nt) {
      bf16x8 bfr = *(const bf16x8*)(Bmsc + (size_t)ks * 2048 + nt * 512 + lane * 8);
      accS[nt] = __builtin_amdgcn_mfma_f32_16x16x32_bf16(af, bfr, accS[nt], 0, 0, 0);
    }
  }
#pragma unroll
  for (int ks = 0; ks < 2; ++ks) {
    bf16x8 af = *(const bf16x8*)(xb + ks * 32);
#pragma unroll
    for (int nt = 0; nt < 4; ++nt) {
      bf16x8 bfrH = *(const bf16x8*)(Bm1 + (size_t)(10 + ks) * 2048 + nt * 512 + lane * 8);
      accH[nt] = __builtin_amdgcn_mfma_f32_16x16x32_bf16(af, bfrH, accH[nt], 0, 0, 0);
      bf16x8 bfrS = *(const bf16x8*)(Bmsc + (size_t)(2 + ks) * 2048 + nt * 512 + lane * 8);
      accS[nt] = __builtin_amdgcn_mfma_f32_16x16x32_bf16(af, bfrS, accS[nt], 0, 0, 0);
    }
  }
  float bvH[4], bvS[4];
#pragma unroll
  for (int nt = 0; nt < 4; ++nt) {
    bvH[nt] = b1[nt * 16 + row16];
    bvS[nt] = bs[nt * 16 + row16];
  }
  float csH[4] = {}, cqH[4] = {}, csS[4] = {}, cqS[4] = {};
#pragma unroll
  for (int r = 0; r < 4; ++r) {
    int orow = rowbase + kg * 4 + r;
    if (orow < M) {
#pragma unroll
      for (int nt = 0; nt < 4; ++nt) {
        float vh = accH[nt][r] + bvH[nt];
        float vs = accS[nt][r] + bvS[nt];
        H[(size_t)orow * 64 + nt * 16 + row16] = f2bf(vh);
        S[(size_t)orow * 64 + nt * 16 + row16] = f2bf(vs);
        csH[nt] += vh;
        cqH[nt] = fmaf(vh, vh, cqH[nt]);
        csS[nt] += vs;
        cqS[nt] = fmaf(vs, vs, cqS[nt]);
      }
    }
  }
  bn_epilogue(csH, cqH, wid, lane, tid, red_s, red_q, sumH, sqH);
  bn_epilogue(csS, cqS, wid, lane, tid, red_s, red_q, sumS, sqS);
}

// normalize + ELU; BN params computed per-block from stats; 4 elems/thread ---
__global__ void norm_elu(const ushortT* __restrict__ Hbf, ushortT* __restrict__ h_bf,
                         const float* __restrict__ stats, const float* __restrict__ gam,
                         const float* __restrict__ bet, float inv_n, int total4) {
  __shared__ float sc_s[64], sh_s[64];
  int tid = threadIdx.x;
  if (tid < 64) {
    float m = stats[tid] * inv_n;
    float v = stats[64 + tid] * inv_n - m * m;
    float r = rsqrtf(v + BN_EPS);
    float s = r * gam[tid];
    sc_s[tid] = s;
    sh_s[tid] = bet[tid] - m * s;
  }
  __syncthreads();
  int t = blockIdx.x * 256 + tid;
  if (t >= total4) return;
  int idx = t * 4;
  int c = idx & 63;
  uint2 hv = *(const uint2*)&Hbf[idx];
  float v0 = bf2f((ushortT)(hv.x & 0xffffu)) * sc_s[c] + sh_s[c];
  float v1 = bf2f((ushortT)(hv.x >> 16)) * sc_s[c + 1] + sh_s[c + 1];
  float v2 = bf2f((ushortT)(hv.y & 0xffffu)) * sc_s[c + 2] + sh_s[c + 2];
  float v3 = bf2f((ushortT)(hv.y >> 16)) * sc_s[c + 3] + sh_s[c + 3];
  v0 = v0 > 0.f ? v0 : expm1f(v0);
  v1 = v1 > 0.f ? v1 : expm1f(v1);
  v2 = v2 > 0.f ? v2 : expm1f(v2);
  v3 = v3 > 0.f ? v3 : expm1f(v3);
  *(uint2*)&h_bf[idx] = make_uint2(pk2(v0, v1), pk2(v2, v3));
}

// final: BN2(h2) + BNsc(sc) + add + ELU; params per-block; fp32 out ----------
__global__ void final_kernel(const ushortT* __restrict__ h2, const ushortT* __restrict__ scb,
                             const float* __restrict__ stats,
                             const float* __restrict__ gam2, const float* __restrict__ bet2,
                             const float* __restrict__ gams, const float* __restrict__ bets,
                             float inv_n, float* __restrict__ out, int total4) {
  __shared__ float s2_s[64], t2_s[64], ss_s[64], ts_s[64];
  int tid = threadIdx.x;
  if (tid < 64) {
    float m = stats[2 * 64 + tid] * inv_n;
    float v = stats[3 * 64 + tid] * inv_n - m * m;
    float r = rsqrtf(v + BN_EPS);
    float s = r * gam2[tid];
    s2_s[tid] = s;
    t2_s[tid] = bet2[tid] - m * s;
  } else if (tid < 128) {
    int c = tid - 64;
    float m = stats[4 * 64 + c] * inv_n;
    float v = stats[5 * 64 + c] * inv_n - m * m;
    float r = rsqrtf(v + BN_EPS);
    float s = r * gams[c];
    ss_s[c] = s;
    ts_s[c] = bets[c] - m * s;
  }
  __syncthreads();
  int t = blockIdx.x * 256 + tid;
  if (t >= total4) return;
  int idx = t * 4;
  int c = idx & 63;
  uint2 hv = *(const uint2*)&h2[idx];
  uint2 sv = *(const uint2*)&scb[idx];
  float v0 = bf2f((ushortT)(hv.x & 0xffffu)) * s2_s[c] + t2_s[c] +
             bf2f((ushortT)(sv.x & 0xffffu)) * ss_s[c] + ts_s[c];
  float v1 = bf2f((ushortT)(hv.x >> 16)) * s2_s[c + 1] + t2_s[c + 1] +
             bf2f((ushortT)(sv.x >> 16)) * ss_s[c + 1] + ts_s[c + 1];
  float v2 = bf2f((ushortT)(hv.y & 0xffffu)) * s2_s[c + 2] + t2_s[c + 2] +
             bf2f((ushortT)(sv.y & 0xffffu)) * ss_s[c + 2] + ts_s[c + 2];
  float v3 = bf2f((ushortT)(hv.y >> 16)) * s2_s[c + 3] + t2_s[c + 3] +
             bf2f((ushortT)(sv.y >> 16)) * ss_s[c + 3] + ts_s[c + 3];
  float4 o;
  o.x = v0 > 0.f ? v0 : expm1f(v0);
  o.y = v1 > 0.f ? v1 : expm1f(v1);
  o.z = v2 > 0.f ? v2 : expm1f(v2);
  o.w = v3 > 0.f ? v3 : expm1f(v3);
  *(float4*)&out[idx] = o;
}

// ---------------------------------------------------------------------------
extern "C" void kernel_launch(void* const* d_in, const int* in_sizes, int n_in,
                              void* d_out, int out_size, void* d_ws, size_t ws_size,
                              hipStream_t stream) {
  const float* x    = (const float*)d_in[0];
  const void*  ei   = d_in[1];
  const float* ea   = (const float*)d_in[2];
  const float* g1   = (const float*)d_in[3];
  const float* mu1  = (const float*)d_in[4];
  const float* sig1 = (const float*)d_in[5];
  const float* root1= (const float*)d_in[6];
  const float* b1   = (const float*)d_in[7];
  const float* gam1 = (const float*)d_in[8];
  const float* bet1 = (const float*)d_in[9];
  const float* g2   = (const float*)d_in[10];
  const float* mu2  = (const float*)d_in[11];
  const float* sig2 = (const float*)d_in[12];
  const float* root2= (const float*)d_in[13];
  const float* b2   = (const float*)d_in[14];
  const float* gam2 = (const float*)d_in[15];
  const float* bet2 = (const float*)d_in[16];
  const float* gs   = (const float*)d_in[17];
  const float* mus  = (const float*)d_in[18];
  const float* sigs = (const float*)d_in[19];
  const float* roots= (const float*)d_in[20];
  const float* bs   = (const float*)d_in[21];
  const float* gams = (const float*)d_in[22];
  const float* bets = (const float*)d_in[23];

  int N = in_sizes[0] / 64;
  int E = in_sizes[1] / 2;

  char* w = (char*)d_ws;
  auto alloc = [&](size_t bytes) {
    char* p = w;
    w += (bytes + 255) & ~(size_t)255;
    return p;
  };
  int*     flag    = (int*)alloc(256);
  int*     cnt     = (int*)alloc((size_t)N * 4);
  uint4*   wbufC   = (uint4*)alloc((size_t)N * PAD * 32); // combined 32B slots
  ushortT* Abuf    = (ushortT*)alloc((size_t)N * 384 * 2); // agg outputs (bf16)
  ushortT* x_bf    = (ushortT*)alloc((size_t)N * 64 * 2);
  ushortT* h_bf    = (ushortT*)alloc((size_t)N * 64 * 2);  // normalized h (bf16)
  ushortT* Hpre    = (ushortT*)alloc((size_t)N * 64 * 2);  // pre-BN layer1 out
  ushortT* scb     = (ushortT*)alloc((size_t)N * 64 * 2);  // pre-BN shortcut out
  ushortT* Bm1     = (ushortT*)alloc(12 * 2048 * 2);       // MFMA-layout B (bf16)
  ushortT* Bm2     = (ushortT*)alloc(12 * 2048 * 2);
  ushortT* Bmsc    = (ushortT*)alloc(4 * 2048 * 2);
  float*   stats   = (float*)alloc(12 * 64 * 4);
  // alias: wbufC dead after agg2 -> h2b (written by gemm_mfma afterwards)
  ushortT* h2b = (ushortT*)wbufC;                          // pre-BN layer2 out

  int eb = (E + 255) / 256;
  int total4 = (N * 64) / 4;
  int nb_e4 = (total4 + 255) / 256;
  float inv_n = 1.0f / (float)N;

  prologue<<<nb_e4, 256, 0, stream>>>(x, x_bf, N * 64, cnt, stats, N, ei, flag,
                                      g1, root1, Bm1, g2, root2, Bm2, gs, roots, Bmsc);

  scatter_wgt<<<eb, 256, 0, stream>>>(ei, ea, E, flag, cnt,
                                      mu1, sig1, mus, sigs, mu2, sig2, wbufC);

  int mtiles = (N + 63) / 64;
  int nb_node16 = (N + 15) / 16;

  // ---- layer1 + shortcut (one dual-MFMA GEMM) ----
  agg_pre<6><<<nb_node16, 256, 0, stream>>>(x_bf, cnt, wbufC, 0, Abuf, N, 384);
  gemm_mfma_dual<<<mtiles, 256, 0, stream>>>(Abuf, x_bf, Bm1, Bmsc, b1, bs, Hpre, scb, N,
                                             stats + 0 * 64, stats + 1 * 64,
                                             stats + 4 * 64, stats + 5 * 64);
  norm_elu<<<nb_e4, 256, 0, stream>>>(Hpre, h_bf, stats, gam1, bet1, inv_n, total4);

  // ---- layer2 ----
  agg_pre<5><<<nb_node16, 256, 0, stream>>>(h_bf, cnt, wbufC, 1, Abuf, N, 320);
  gemm_mfma<<<mtiles, 256, 0, stream>>>(Abuf, 320, 320, h_bf, Bm2, b2, h2b, N,
                                        stats + 2 * 64, stats + 3 * 64);

  final_kernel<<<nb_e4, 256, 0, stream>>>(h2b, scb, stats, gam2, bet2, gams, bets,
                                          inv_n, (float*)d_out, total4);
}

// Round 25
// 186.752 us; speedup vs baseline: 1.1806x; 1.1806x over previous
//
#include <hip/hip_runtime.h>
#include <hip/hip_bf16.h>

// ---------------------------------------------------------------------------
// ResidualBlock: GMMConv(x)->BN->ELU->GMMConv->BN  +  GMMConv_sc(x)->BN ; ELU
// N=50000, E=800000, C=64, K_main=5, K_sc=1.
// Round 25: REVERT round-24's nontemporal stores (L2 was coalescing the two
// 16B record halves; nt-stores forced partial-line HBM writes: 52->65MB,
// scatter 50->74us). This is the exact round-21 configuration = session best
// (187.1us): plain stores, atomic-hoisted scatter, quarter-wave agg,
// dual-MFMA GEMMs, BN fused in epilogues.
// ---------------------------------------------------------------------------

#define EPS_SIGMA 1e-15f
#define BN_EPS    1e-5f
#define PAD       48

typedef unsigned short ushortT;
typedef unsigned int uintT;
typedef __attribute__((ext_vector_type(8))) short bf16x8;
typedef __attribute__((ext_vector_type(4))) float f32x4;
typedef __attribute__((ext_vector_type(2))) float f32x2;

__device__ __forceinline__ ushortT f2bf(float f) {
  uintT b = __float_as_uint(f);
  b += 0x7FFFu + ((b >> 16) & 1u);   // round-to-nearest-even
  return (ushortT)(b >> 16);
}
__device__ __forceinline__ float bf2f(ushortT u) {
  return __uint_as_float(((uintT)u) << 16);
}
__device__ __forceinline__ uintT pk2(float a, float b) {
  return (uintT)f2bf(a) | ((uintT)f2bf(b) << 16);
}

// --- B prep helper: pack [G;root] into MFMA B-fragment layout (bf16) --------
__device__ __forceinline__ void prep_one(const float* __restrict__ g,
                                         const float* __restrict__ root,
                                         ushortT* __restrict__ Bm, int K, int t) {
  int ks = t >> 8, rem = t & 255;
  int nt = rem >> 6, lane = rem & 63;
  int kbase = ks * 32 + (lane >> 4) * 8;
  int col = nt * 16 + (lane & 15);
  ushortT o[8];
#pragma unroll
  for (int j = 0; j < 8; ++j) {
    int r = kbase + j;
    float v;
    if (r < K * 64) {
      int k = r >> 6, i = r & 63;
      v = g[(size_t)i * (K * 64) + k * 64 + col];
    } else {
      v = root[(size_t)(r - K * 64) * 64 + col];
    }
    o[j] = f2bf(v);
  }
  *(uint4*)&Bm[(size_t)t * 8] = *(const uint4*)o;
}

// --- prologue: x->bf16, zero cnt/stats, detect dtype, prep B matrices -------
__global__ void prologue(const float* __restrict__ x, ushortT* __restrict__ x_bf,
                         int total, int* __restrict__ cnt, float* __restrict__ stats,
                         int n, const void* ei, int* flag,
                         const float* g1, const float* root1, ushortT* Bm1,
                         const float* g2, const float* root2, ushortT* Bm2,
                         const float* gs, const float* roots, ushortT* Bmsc) {
  int t = blockIdx.x * 256 + threadIdx.x;
  int idx = t * 4;
  if (idx + 3 < total) {
    float4 v = *(const float4*)&x[idx];
    ushortT o[4] = {f2bf(v.x), f2bf(v.y), f2bf(v.z), f2bf(v.w)};
    *(uint2*)&x_bf[idx] = *(const uint2*)o;
  }
  if (t < n) cnt[t] = 0;
  if (t < 12 * 64) stats[t] = 0.f;
  if (blockIdx.x < 12) prep_one(g1, root1, Bm1, 5, t);
  else if (blockIdx.x < 24) prep_one(g2, root2, Bm2, 5, t - 12 * 256);
  else if (blockIdx.x < 28) prep_one(gs, roots, Bmsc, 1, t - 24 * 256);
  else if (blockIdx.x == 28) {
    const int* p = (const int*)ei;
    __shared__ int bad;
    if (threadIdx.x == 0) bad = 0;
    __syncthreads();
    if (p[threadIdx.x * 2 + 1] != 0) atomicAdd(&bad, 1);
    __syncthreads();
    if (threadIdx.x == 0) *flag = (bad == 0);  // 1 => int64 layout
  }
}

__device__ __forceinline__ int load_idx(const void* ei, size_t pos, int is64) {
  if (is64) return (int)((const long long*)ei)[pos];
  return ((const int*)ei)[pos];
}

// --- scatter + gaussian weights: 32B combined slot in PADDED region ---------
__global__ __launch_bounds__(256) void scatter_wgt(
    const void* ei, const float* __restrict__ ea, int E, const int* flag,
    int* __restrict__ cnt,
    const float* __restrict__ mu1, const float* __restrict__ sig1,
    const float* __restrict__ mus, const float* __restrict__ sigs,
    const float* __restrict__ mu2, const float* __restrict__ sig2,
    uint4* __restrict__ wbufC) {
  int e = blockIdx.x * 256 + threadIdx.x;
  if (e >= E) return;
  int is64 = *flag;
  int s = load_idx(ei, (size_t)e, is64);
  int d = load_idx(ei, (size_t)E + e, is64);
  float p = ea[e];
  // atomic first: round-trip overlaps the 11 independent exps below
  int pos = atomicAdd(&cnt[d], 1);
  float w1[6], w2[5];
#pragma unroll
  for (int k = 0; k < 5; ++k) {
    float sg = sig1[k], df = p - mu1[k];
    w1[k] = __expf(-0.5f / (EPS_SIGMA + sg * sg) * df * df);
  }
  {
    float sg = sigs[0], df = p - mus[0];
    w1[5] = __expf(-0.5f / (EPS_SIGMA + sg * sg) * df * df);
  }
#pragma unroll
  for (int k = 0; k < 5; ++k) {
    float sg = sig2[k], df = p - mu2[k];
    w2[k] = __expf(-0.5f / (EPS_SIGMA + sg * sg) * df * df);
  }
  if (pos < PAD) {
    size_t slot = (size_t)d * PAD + pos;
    wbufC[slot * 2 + 0] = make_uint4(pk2(w1[0], w1[1]), pk2(w1[2], w1[3]),
                                     pk2(w1[4], w1[5]), (uintT)s);
    wbufC[slot * 2 + 1] = make_uint4(pk2(w2[0], w2[1]), pk2(w2[2], w2[3]),
                                     pk2(w2[4], 0.f), (uintT)s);
  }
}

// --- aggregation: QUARTER-wave per node; lane = 4 channels; no cross-lane ---
template <int KT>
__device__ __forceinline__ void q_fma(f32x2* acc, uint4 r, uint2 xv) {
  f32x2 xlo, xhi;
  xlo.x = bf2f((ushortT)(xv.x & 0xffffu));
  xlo.y = bf2f((ushortT)(xv.x >> 16));
  xhi.x = bf2f((ushortT)(xv.y & 0xffffu));
  xhi.y = bf2f((ushortT)(xv.y >> 16));
  float w;
  f32x2 wv;
  w = bf2f((ushortT)(r.x & 0xffffu));
  wv.x = w; wv.y = w;
  acc[0] = __builtin_elementwise_fma(wv, xlo, acc[0]);
  acc[1] = __builtin_elementwise_fma(wv, xhi, acc[1]);
  if (KT > 1) {
    w = bf2f((ushortT)(r.x >> 16));
    wv.x = w; wv.y = w;
    acc[2] = __builtin_elementwise_fma(wv, xlo, acc[2]);
    acc[3] = __builtin_elementwise_fma(wv, xhi, acc[3]);
  }
  if (KT > 2) {
    w = bf2f((ushortT)(r.y & 0xffffu));
    wv.x = w; wv.y = w;
    acc[4] = __builtin_elementwise_fma(wv, xlo, acc[4]);
    acc[5] = __builtin_elementwise_fma(wv, xhi, acc[5]);
  }
  if (KT > 3) {
    w = bf2f((ushortT)(r.y >> 16));
    wv.x = w; wv.y = w;
    acc[6] = __builtin_elementwise_fma(wv, xlo, acc[6]);
    acc[7] = __builtin_elementwise_fma(wv, xhi, acc[7]);
  }
  if (KT > 4) {
    w = bf2f((ushortT)(r.z & 0xffffu));
    wv.x = w; wv.y = w;
    acc[8] = __builtin_elementwise_fma(wv, xlo, acc[8]);
    acc[9] = __builtin_elementwise_fma(wv, xhi, acc[9]);
  }
  if (KT > 5) {
    w = bf2f((ushortT)(r.z >> 16));
    wv.x = w; wv.y = w;
    acc[10] = __builtin_elementwise_fma(wv, xlo, acc[10]);
    acc[11] = __builtin_elementwise_fma(wv, xhi, acc[11]);
  }
}

// off = 0 (layer1+sc record) or 1 (layer2 record) within each 32B slot
template <int KT>
__global__ __launch_bounds__(256) void agg_pre(const ushortT* __restrict__ feat,
                                               const int* __restrict__ cnt,
                                               const uint4* __restrict__ wbufC, int off,
                                               ushortT* __restrict__ out, int n, int ldo) {
  int lane = threadIdx.x & 63;
  int q = lane >> 4;     // quarter index: which node of this wave's 4
  int c4 = lane & 15;    // channel group: channels 4*c4 .. 4*c4+3
  int node = (blockIdx.x * 4 + (threadIdx.x >> 6)) * 4 + q;  // 16 nodes/block
  bool act = node < n;
  int deg = act ? cnt[node] : 0;
  int cap = deg < PAD ? deg : PAD;
  int beg = node * PAD;
  int end = beg + cap;
  f32x2 acc[2 * KT];
#pragma unroll
  for (int k = 0; k < 2 * KT; ++k) acc[k] = (f32x2){0.f, 0.f};
  int i = beg;
  // unroll 4: per quarter 4 records + 4 gathers in flight (16 loads/wave)
  for (; i + 4 <= end; i += 4) {
    uint4 r0 = wbufC[(size_t)(i + 0) * 2 + off];
    uint4 r1 = wbufC[(size_t)(i + 1) * 2 + off];
    uint4 r2 = wbufC[(size_t)(i + 2) * 2 + off];
    uint4 r3 = wbufC[(size_t)(i + 3) * 2 + off];
    uint2 x0 = *(const uint2*)&feat[((size_t)r0.w << 6) + c4 * 4];
    uint2 x1 = *(const uint2*)&feat[((size_t)r1.w << 6) + c4 * 4];
    uint2 x2 = *(const uint2*)&feat[((size_t)r2.w << 6) + c4 * 4];
    uint2 x3 = *(const uint2*)&feat[((size_t)r3.w << 6) + c4 * 4];
    q_fma<KT>(acc, r0, x0);
    q_fma<KT>(acc, r1, x1);
    q_fma<KT>(acc, r2, x2);
    q_fma<KT>(acc, r3, x3);
  }
  for (; i < end; ++i) {
    uint4 r = wbufC[(size_t)i * 2 + off];
    uint2 xv = *(const uint2*)&feat[((size_t)r.w << 6) + c4 * 4];
    q_fma<KT>(acc, r, xv);
  }
  if (act) {
    float invdeg = 1.0f / (float)(deg > 1 ? deg : 1);
    uintT* outu = (uintT*)out;
    size_t obase = ((size_t)node * ldo) >> 1;
#pragma unroll
    for (int k = 0; k < KT; ++k) {
      uint2 ov = make_uint2(pk2(acc[2 * k].x * invdeg, acc[2 * k].y * invdeg),
                            pk2(acc[2 * k + 1].x * invdeg, acc[2 * k + 1].y * invdeg));
      *(uint2*)&outu[obase + k * 32 + c4 * 2] = ov;
    }
  }
}

// --- BN-stats epilogue helper (device, per-block) ---------------------------
__device__ __forceinline__ void bn_epilogue(float cs[4], float cq[4], int wid, int lane,
                                            int tid, float red_s[4][64], float red_q[4][64],
                                            float* sums, float* sumsq) {
#pragma unroll
  for (int nt = 0; nt < 4; ++nt) {
    cs[nt] += __shfl_xor(cs[nt], 16);
    cs[nt] += __shfl_xor(cs[nt], 32);
    cq[nt] += __shfl_xor(cq[nt], 16);
    cq[nt] += __shfl_xor(cq[nt], 32);
  }
  if (lane < 16) {
#pragma unroll
    for (int nt = 0; nt < 4; ++nt) {
      red_s[wid][nt * 16 + lane] = cs[nt];
      red_q[wid][nt * 16 + lane] = cq[nt];
    }
  }
  __syncthreads();
  if (tid < 64) {
    float ts = red_s[0][tid] + red_s[1][tid] + red_s[2][tid] + red_s[3][tid];
    float tq = red_q[0][tid] + red_q[1][tid] + red_q[2][tid] + red_q[3][tid];
    atomicAdd(&sums[tid], ts);
    atomicAdd(&sumsq[tid], tq);
  }
  __syncthreads();
}

// --- MFMA GEMM (single): Cbf[M,64] = [A1(K1)|A2(64)]@B + bias ; BN stats ----
__global__ __launch_bounds__(256) void gemm_mfma(const ushortT* __restrict__ A1, int lda1,
                                                 int K1, const ushortT* __restrict__ A2,
                                                 const ushortT* __restrict__ Bm,
                                                 const float* __restrict__ bias,
                                                 ushortT* __restrict__ C, int M,
                                                 float* sums, float* sumsq) {
  __shared__ float red_s[4][64];
  __shared__ float red_q[4][64];
  int tid = threadIdx.x;
  int wid = tid >> 6, lane = tid & 63;
  int row16 = lane & 15, kg = lane >> 4;
  int rowbase = blockIdx.x * 64 + wid * 16;
  int arow = rowbase + row16;
  if (arow >= M) arow = M - 1;
  const ushortT* a1p = A1 + (size_t)arow * lda1 + kg * 8;
  const ushortT* a2p = A2 + (size_t)arow * 64 + kg * 8;
  int nks1 = K1 >> 5;
  int nks = (K1 + 64) >> 5;
  f32x4 acc[4];
#pragma unroll
  for (int nt = 0; nt < 4; ++nt) acc[nt] = (f32x4){0.f, 0.f, 0.f, 0.f};
  for (int ks = 0; ks < nks; ++ks) {
    const ushortT* ap = (ks < nks1) ? (a1p + ks * 32) : (a2p + (ks - nks1) * 32);
    bf16x8 af = *(const bf16x8*)ap;
#pragma unroll
    for (int nt = 0; nt < 4; ++nt) {
      bf16x8 bfr = *(const bf16x8*)(Bm + (size_t)ks * 2048 + nt * 512 + lane * 8);
      acc[nt] = __builtin_amdgcn_mfma_f32_16x16x32_bf16(af, bfr, acc[nt], 0, 0, 0);
    }
  }
  float bv[4];
#pragma unroll
  for (int nt = 0; nt < 4; ++nt) bv[nt] = bias[nt * 16 + row16];
  float cs[4] = {}, cq[4] = {};
#pragma unroll
  for (int r = 0; r < 4; ++r) {
    int orow = rowbase + kg * 4 + r;
    if (orow < M) {
#pragma unroll
      for (int nt = 0; nt < 4; ++nt) {
        float v = acc[nt][r] + bv[nt];
        C[(size_t)orow * 64 + nt * 16 + row16] = f2bf(v);
        cs[nt] += v;
        cq[nt] = fmaf(v, v, cq[nt]);
      }
    }
  }
  bn_epilogue(cs, cq, wid, lane, tid, red_s, red_q, sums, sumsq);
}

// --- MFMA GEMM (dual): Hbf = [Abuf|x]@Bm1+b1 ; Sbf = [Abuf_sc|x]@Bmsc+bs ----
__global__ __launch_bounds__(256) void gemm_mfma_dual(
    const ushortT* __restrict__ Abuf, const ushortT* __restrict__ X,
    const ushortT* __restrict__ Bm1, const ushortT* __restrict__ Bmsc,
    const float* __restrict__ b1, const float* __restrict__ bs,
    ushortT* __restrict__ H, ushortT* __restrict__ S, int M,
    float* sumH, float* sqH, float* sumS, float* sqS) {
  __shared__ float red_s[4][64];
  __shared__ float red_q[4][64];
  int tid = threadIdx.x;
  int wid = tid >> 6, lane = tid & 63;
  int row16 = lane & 15, kg = lane >> 4;
  int rowbase = blockIdx.x * 64 + wid * 16;
  int arow = rowbase + row16;
  if (arow >= M) arow = M - 1;
  const ushortT* ab = Abuf + (size_t)arow * 384 + kg * 8;
  const ushortT* xb = X + (size_t)arow * 64 + kg * 8;
  f32x4 accH[4], accS[4];
#pragma unroll
  for (int nt = 0; nt < 4; ++nt) {
    accH[nt] = (f32x4){0.f, 0.f, 0.f, 0.f};
    accS[nt] = (f32x4){0.f, 0.f, 0.f, 0.f};
  }
  for (int ks = 0; ks < 10; ++ks) {
    bf16x8 af = *(const bf16x8*)(ab + ks * 32);
#pragma unroll
    for (int nt = 0; nt < 4; ++nt) {
      bf16x8 bfr = *(const bf16x8*)(Bm1 + (size_t)ks * 2048 + nt * 512 + lane * 8);
      accH[nt] = __builtin_amdgcn_mfma_f32_16x16x32_bf16(af, bfr, accH[nt], 0, 0, 0);
    }
  }
#pragma unroll
  for (int ks = 0; ks < 2; ++ks) {
    bf16x8 af = *(const bf16x8*)(ab + 320 + ks * 32);
#pragma unroll
    for (int nt = 0; nt < 4; ++nt) {
      bf16x8 bfr = *(const bf16x8*)(Bmsc + (size_t)ks * 2048 + nt * 512 + lane * 8);
      accS[nt] = __builtin_amdgcn_mfma_f32_16x16x32_bf16(af, bfr, accS[nt], 0, 0, 0);
    }
  }
#pragma unroll
  for (int ks = 0; ks < 2; ++ks) {
    bf16x8 af = *(const bf16x8*)(xb + ks * 32);
#pragma unroll
    for (int nt = 0; nt < 4; ++nt) {
      bf16x8 bfrH = *(const bf16x8*)(Bm1 + (size_t)(10 + ks) * 2048 + nt * 512 + lane * 8);
      accH[nt] = __builtin_amdgcn_mfma_f32_16x16x32_bf16(af, bfrH, accH[nt], 0, 0, 0);
      bf16x8 bfrS = *(const bf16x8*)(Bmsc + (size_t)(2 + ks) * 2048 + nt * 512 + lane * 8);
      accS[nt] = __builtin_amdgcn_mfma_f32_16x16x32_bf16(af, bfrS, accS[nt], 0, 0, 0);
    }
  }
  float bvH[4], bvS[4];
#pragma unroll
  for (int nt = 0; nt < 4; ++nt) {
    bvH[nt] = b1[nt * 16 + row16];
    bvS[nt] = bs[nt * 16 + row16];
  }
  float csH[4] = {}, cqH[4] = {}, csS[4] = {}, cqS[4] = {};
#pragma unroll
  for (int r = 0; r < 4; ++r) {
    int orow = rowbase + kg * 4 + r;
    if (orow < M) {
#pragma unroll
      for (int nt = 0; nt < 4; ++nt) {
        float vh = accH[nt][r] + bvH[nt];
        float vs = accS[nt][r] + bvS[nt];
        H[(size_t)orow * 64 + nt * 16 + row16] = f2bf(vh);
        S[(size_t)orow * 64 + nt * 16 + row16] = f2bf(vs);
        csH[nt] += vh;
        cqH[nt] = fmaf(vh, vh, cqH[nt]);
        csS[nt] += vs;
        cqS[nt] = fmaf(vs, vs, cqS[nt]);
      }
    }
  }
  bn_epilogue(csH, cqH, wid, lane, tid, red_s, red_q, sumH, sqH);
  bn_epilogue(csS, cqS, wid, lane, tid, red_s, red_q, sumS, sqS);
}

// normalize + ELU; BN params computed per-block from stats; 4 elems/thread ---
__global__ void norm_elu(const ushortT* __restrict__ Hbf, ushortT* __restrict__ h_bf,
                         const float* __restrict__ stats, const float* __restrict__ gam,
                         const float* __restrict__ bet, float inv_n, int total4) {
  __shared__ float sc_s[64], sh_s[64];
  int tid = threadIdx.x;
  if (tid < 64) {
    float m = stats[tid] * inv_n;
    float v = stats[64 + tid] * inv_n - m * m;
    float r = rsqrtf(v + BN_EPS);
    float s = r * gam[tid];
    sc_s[tid] = s;
    sh_s[tid] = bet[tid] - m * s;
  }
  __syncthreads();
  int t = blockIdx.x * 256 + tid;
  if (t >= total4) return;
  int idx = t * 4;
  int c = idx & 63;
  uint2 hv = *(const uint2*)&Hbf[idx];
  float v0 = bf2f((ushortT)(hv.x & 0xffffu)) * sc_s[c] + sh_s[c];
  float v1 = bf2f((ushortT)(hv.x >> 16)) * sc_s[c + 1] + sh_s[c + 1];
  float v2 = bf2f((ushortT)(hv.y & 0xffffu)) * sc_s[c + 2] + sh_s[c + 2];
  float v3 = bf2f((ushortT)(hv.y >> 16)) * sc_s[c + 3] + sh_s[c + 3];
  v0 = v0 > 0.f ? v0 : expm1f(v0);
  v1 = v1 > 0.f ? v1 : expm1f(v1);
  v2 = v2 > 0.f ? v2 : expm1f(v2);
  v3 = v3 > 0.f ? v3 : expm1f(v3);
  *(uint2*)&h_bf[idx] = make_uint2(pk2(v0, v1), pk2(v2, v3));
}

// final: BN2(h2) + BNsc(sc) + add + ELU; params per-block; fp32 out ----------
__global__ void final_kernel(const ushortT* __restrict__ h2, const ushortT* __restrict__ scb,
                             const float* __restrict__ stats,
                             const float* __restrict__ gam2, const float* __restrict__ bet2,
                             const float* __restrict__ gams, const float* __restrict__ bets,
                             float inv_n, float* __restrict__ out, int total4) {
  __shared__ float s2_s[64], t2_s[64], ss_s[64], ts_s[64];
  int tid = threadIdx.x;
  if (tid < 64) {
    float m = stats[2 * 64 + tid] * inv_n;
    float v = stats[3 * 64 + tid] * inv_n - m * m;
    float r = rsqrtf(v + BN_EPS);
    float s = r * gam2[tid];
    s2_s[tid] = s;
    t2_s[tid] = bet2[tid] - m * s;
  } else if (tid < 128) {
    int c = tid - 64;
    float m = stats[4 * 64 + c] * inv_n;
    float v = stats[5 * 64 + c] * inv_n - m * m;
    float r = rsqrtf(v + BN_EPS);
    float s = r * gams[c];
    ss_s[c] = s;
    ts_s[c] = bets[c] - m * s;
  }
  __syncthreads();
  int t = blockIdx.x * 256 + tid;
  if (t >= total4) return;
  int idx = t * 4;
  int c = idx & 63;
  uint2 hv = *(const uint2*)&h2[idx];
  uint2 sv = *(const uint2*)&scb[idx];
  float v0 = bf2f((ushortT)(hv.x & 0xffffu)) * s2_s[c] + t2_s[c] +
             bf2f((ushortT)(sv.x & 0xffffu)) * ss_s[c] + ts_s[c];
  float v1 = bf2f((ushortT)(hv.x >> 16)) * s2_s[c + 1] + t2_s[c + 1] +
             bf2f((ushortT)(sv.x >> 16)) * ss_s[c + 1] + ts_s[c + 1];
  float v2 = bf2f((ushortT)(hv.y & 0xffffu)) * s2_s[c + 2] + t2_s[c + 2] +
             bf2f((ushortT)(sv.y & 0xffffu)) * ss_s[c + 2] + ts_s[c + 2];
  float v3 = bf2f((ushortT)(hv.y >> 16)) * s2_s[c + 3] + t2_s[c + 3] +
             bf2f((ushortT)(sv.y >> 16)) * ss_s[c + 3] + ts_s[c + 3];
  float4 o;
  o.x = v0 > 0.f ? v0 : expm1f(v0);
  o.y = v1 > 0.f ? v1 : expm1f(v1);
  o.z = v2 > 0.f ? v2 : expm1f(v2);
  o.w = v3 > 0.f ? v3 : expm1f(v3);
  *(float4*)&out[idx] = o;
}

// ---------------------------------------------------------------------------
extern "C" void kernel_launch(void* const* d_in, const int* in_sizes, int n_in,
                              void* d_out, int out_size, void* d_ws, size_t ws_size,
                              hipStream_t stream) {
  const float* x    = (const float*)d_in[0];
  const void*  ei   = d_in[1];
  const float* ea   = (const float*)d_in[2];
  const float* g1   = (const float*)d_in[3];
  const float* mu1  = (const float*)d_in[4];
  const float* sig1 = (const float*)d_in[5];
  const float* root1= (const float*)d_in[6];
  const float* b1   = (const float*)d_in[7];
  const float* gam1 = (const float*)d_in[8];
  const float* bet1 = (const float*)d_in[9];
  const float* g2   = (const float*)d_in[10];
  const float* mu2  = (const float*)d_in[11];
  const float* sig2 = (const float*)d_in[12];
  const float* root2= (const float*)d_in[13];
  const float* b2   = (const float*)d_in[14];
  const float* gam2 = (const float*)d_in[15];
  const float* bet2 = (const float*)d_in[16];
  const float* gs   = (const float*)d_in[17];
  const float* mus  = (const float*)d_in[18];
  const float* sigs = (const float*)d_in[19];
  const float* roots= (const float*)d_in[20];
  const float* bs   = (const float*)d_in[21];
  const float* gams = (const float*)d_in[22];
  const float* bets = (const float*)d_in[23];

  int N = in_sizes[0] / 64;
  int E = in_sizes[1] / 2;

  char* w = (char*)d_ws;
  auto alloc = [&](size_t bytes) {
    char* p = w;
    w += (bytes + 255) & ~(size_t)255;
    return p;
  };
  int*     flag    = (int*)alloc(256);
  int*     cnt     = (int*)alloc((size_t)N * 4);
  uint4*   wbufC   = (uint4*)alloc((size_t)N * PAD * 32); // combined 32B slots
  ushortT* Abuf    = (ushortT*)alloc((size_t)N * 384 * 2); // agg outputs (bf16)
  ushortT* x_bf    = (ushortT*)alloc((size_t)N * 64 * 2);
  ushortT* h_bf    = (ushortT*)alloc((size_t)N * 64 * 2);  // normalized h (bf16)
  ushortT* Hpre    = (ushortT*)alloc((size_t)N * 64 * 2);  // pre-BN layer1 out
  ushortT* scb     = (ushortT*)alloc((size_t)N * 64 * 2);  // pre-BN shortcut out
  ushortT* Bm1     = (ushortT*)alloc(12 * 2048 * 2);       // MFMA-layout B (bf16)
  ushortT* Bm2     = (ushortT*)alloc(12 * 2048 * 2);
  ushortT* Bmsc    = (ushortT*)alloc(4 * 2048 * 2);
  float*   stats   = (float*)alloc(12 * 64 * 4);
  // alias: wbufC dead after agg2 -> h2b (written by gemm_mfma afterwards)
  ushortT* h2b = (ushortT*)wbufC;                          // pre-BN layer2 out

  int eb = (E + 255) / 256;
  int total4 = (N * 64) / 4;
  int nb_e4 = (total4 + 255) / 256;
  float inv_n = 1.0f / (float)N;

  prologue<<<nb_e4, 256, 0, stream>>>(x, x_bf, N * 64, cnt, stats, N, ei, flag,
                                      g1, root1, Bm1, g2, root2, Bm2, gs, roots, Bmsc);

  scatter_wgt<<<eb, 256, 0, stream>>>(ei, ea, E, flag, cnt,
                                      mu1, sig1, mus, sigs, mu2, sig2, wbufC);

  int mtiles = (N + 63) / 64;
  int nb_node16 = (N + 15) / 16;

  // ---- layer1 + shortcut (one dual-MFMA GEMM) ----
  agg_pre<6><<<nb_node16, 256, 0, stream>>>(x_bf, cnt, wbufC, 0, Abuf, N, 384);
  gemm_mfma_dual<<<mtiles, 256, 0, stream>>>(Abuf, x_bf, Bm1, Bmsc, b1, bs, Hpre, scb, N,
                                             stats + 0 * 64, stats + 1 * 64,
                                             stats + 4 * 64, stats + 5 * 64);
  norm_elu<<<nb_e4, 256, 0, stream>>>(Hpre, h_bf, stats, gam1, bet1, inv_n, total4);

  // ---- layer2 ----
  agg_pre<5><<<nb_node16, 256, 0, stream>>>(h_bf, cnt, wbufC, 1, Abuf, N, 320);
  gemm_mfma<<<mtiles, 256, 0, stream>>>(Abuf, 320, 320, h_bf, Bm2, b2, h2b, N,
                                        stats + 2 * 64, stats + 3 * 64);

  final_kernel<<<nb_e4, 256, 0, stream>>>(h2b, scb, stats, gam2, bet2, gams, bets,
                                          inv_n, (float*)d_out, total4);
}